// Round 12
// baseline (1422.592 us; speedup 1.0000x reference)
//
#include <hip/hip_runtime.h>
#include <hip/hip_bf16.h>

#define M_MAPS 4096
#define F_DIM  256
#define NPOOL  256
#define NBATCH 4
#define BM     16          // correlation rows per block (one MFMA M-tile)
#define THREADS 512
#define NT     32          // n-tiles per wave: 4096 / (8 waves * 16 cols)
#define VPT    64          // sort elements per lane (one wave sorts one row)

typedef __attribute__((ext_vector_type(8))) short bf16x8;
typedef __attribute__((ext_vector_type(4))) float f32x4;

__device__ __forceinline__ unsigned short f2bf_bits(float f) {
    __hip_bfloat16 h = __float2bfloat16(f);
    return __builtin_bit_cast(unsigned short, h);
}
__device__ __forceinline__ float bf_bits2f(unsigned short s) {
    __hip_bfloat16 h = __builtin_bit_cast(__hip_bfloat16, s);
    return __bfloat162float(h);
}

// ---------- pre-kernel: split fp32 x into bf16 hi + bf16 lo ----------
__global__ __launch_bounds__(256)
void cvt_split_kernel(const float* __restrict__ x, unsigned short* __restrict__ hi,
                      unsigned short* __restrict__ lo) {
    const int n4 = NBATCH * M_MAPS * F_DIM / 4;
    for (int i = blockIdx.x * blockDim.x + threadIdx.x; i < n4;
         i += gridDim.x * blockDim.x) {
        float4 v = ((const float4*)x)[i];
        float f[4] = {v.x, v.y, v.z, v.w};
        unsigned short h[4], l[4];
        #pragma unroll
        for (int j = 0; j < 4; ++j) {
            h[j] = f2bf_bits(f[j]);
            l[j] = f2bf_bits(f[j] - bf_bits2f(h[j]));
        }
        ((ushort4*)hi)[i] = make_ushort4(h[0], h[1], h[2], h[3]);
        ((ushort4*)lo)[i] = make_ushort4(l[0], l[1], l[2], l[3]);
    }
}

// branchless compare-exchange; desc==true keeps the larger value in `a`.
__device__ __forceinline__ void ce(float& a, float& b, bool desc) {
    float lo = fminf(a, b), hi = fmaxf(a, b);
    a = desc ? hi : lo;
    b = desc ? lo : hi;
}

// ---------- main kernel: MFMA corr + wave-private register bitonic sort ----------
// __launch_bounds__(512, 1): LDS (128 KB) already caps at 1 block/CU = 2
// waves/SIMD, so the allocator may use the full 256-reg/wave budget. The
// round-10 run with (512, 2) capped VGPRs at 128 and spilled ~90 regs/thread
// (+584 MB scratch traffic: WRITE 16->400 MB, FETCH 62->262 MB).
template<int WS>
__global__ __launch_bounds__(THREADS, 1)
void corr_mfma_sort_kernel(const float* __restrict__ x,
                           const unsigned short* __restrict__ hi,
                           const unsigned short* __restrict__ lo,
                           float* __restrict__ out) {
    __shared__ float rows[8 * M_MAPS];   // 128 KB: 8 rows per dump phase

    const int tid  = threadIdx.x;
    const int lane = tid & 63;
    const int w    = tid >> 6;                    // wave 0..7
    const int g    = blockIdx.x;
    // XCD-aware mapping: 2 XCDs per batch so each batch panel stays L2-local
    const int b    = (g & 7) >> 1;                // batch 0..3
    const int gi   = ((g >> 3) << 1) | (g & 1);   // 0..255 within batch
    const int m0   = gi * BM;

    const int lr = lane & 15;                     // A-row / B-col within tile
    const int lg = lane >> 4;                     // k-group 0..3
    const int base = b * (M_MAPS * F_DIM);

    auto load_hl = [&](int off, bf16x8& oh, bf16x8& ol) {
        if constexpr (WS) {
            oh = *(const bf16x8*)(hi + base + off);
            ol = *(const bf16x8*)(lo + base + off);
        } else {
            const float* p = x + base + off;
            float4 f0 = *(const float4*)(p);
            float4 f1 = *(const float4*)(p + 4);
            float f[8] = {f0.x,f0.y,f0.z,f0.w, f1.x,f1.y,f1.z,f1.w};
            #pragma unroll
            for (int e = 0; e < 8; ++e) {
                unsigned short hbit = f2bf_bits(f[e]);
                oh[e] = (short)hbit;
                ol[e] = (short)f2bf_bits(f[e] - bf_bits2f(hbit));
            }
        }
    };

    // ---- A fragments: block's 16 rows, K=256 (8 chunks), hi+lo ----
    bf16x8 a_hi[8], a_lo[8];
    #pragma unroll
    for (int kk = 0; kk < 8; ++kk)
        load_hl((m0 + lr) * F_DIM + kk * 32 + lg * 8, a_hi[kk], a_lo[kk]);

    // ---- GEMM: 16 x 4096, registers only (identical to round-7 pass) ----
    f32x4 acc[NT];
    #pragma unroll
    for (int t = 0; t < NT; ++t) acc[t] = (f32x4){0.f, 0.f, 0.f, 0.f};

    #pragma unroll
    for (int t = 0; t < NT; ++t) {
        const int n = t * 128 + w * 16 + lr;
        const int rowoff = n * F_DIM + lg * 8;
        #pragma unroll
        for (int kk = 0; kk < 8; ++kk) {
            bf16x8 b_hi, b_lo;
            load_hl(rowoff + kk * 32, b_hi, b_lo);
            acc[t] = __builtin_amdgcn_mfma_f32_16x16x32_bf16(a_hi[kk], b_hi, acc[t], 0, 0, 0);
            acc[t] = __builtin_amdgcn_mfma_f32_16x16x32_bf16(a_lo[kk], b_hi, acc[t], 0, 0, 0);
            acc[t] = __builtin_amdgcn_mfma_f32_16x16x32_bf16(a_hi[kk], b_lo, acc[t], 0, 0, 0);
            acc[t] = __builtin_amdgcn_mfma_f32_16x16x32_bf16(a_lo[kk], b_lo, acc[t], 0, 0, 0);
        }
    }

    // ---- two phases: dump 8 rows -> each wave sorts one row in registers ----
    const float scale = 1.0f / F_DIM;
    float v[VPT];

    for (int p = 0; p < 2; ++p) {
        // dump C-rows 8p..8p+7 (lanes lg==2p,2p+1). Column-swizzled:
        // pos(c) = c ^ (((c>>6)&15)<<2) — spreads banks, keeps 16B chunks.
        if ((lg >> 1) == p) {
            #pragma unroll
            for (int t = 0; t < NT; ++t) {
                const int c  = t * 128 + w * 16 + lr;
                const int pc = c ^ (((c >> 6) & 15) << 2);
                #pragma unroll
                for (int j = 0; j < 4; ++j)
                    rows[((lg & 1) * 4 + j) * M_MAPS + pc] = acc[t][j] * scale;
            }
        }
        __syncthreads();

        // wave w loads its row (C-row 8p+w): 16 x ds_read_b128, conflict-light
        #pragma unroll
        for (int i = 0; i < 16; ++i) {
            const int c  = lane * VPT + i * 4;
            const int pc = c ^ ((lane & 15) << 2);   // (c>>6)&15 == lane&15
            f32x4 q = *(const f32x4*)&rows[w * M_MAPS + pc];
            v[i*4+0] = q[0]; v[i*4+1] = q[1]; v[i*4+2] = q[2]; v[i*4+3] = q[3];
        }
        __syncthreads();   // all reads done -> LDS free for next phase's dump

        // ---- wave-private descending bitonic sort of 4096 = 64 lanes x 64 ----
        // global index idx = lane*64 + e
        // k = 2..32: intra-thread, direction compile-time per element
        #pragma unroll
        for (int k = 2; k <= 32; k <<= 1)
            #pragma unroll
            for (int j = k >> 1; j > 0; j >>= 1)
                #pragma unroll
                for (int e = 0; e < VPT; ++e) {
                    const int f = e ^ j;
                    if (f > e) ce(v[e], v[f], (e & k) == 0);
                }
        // k = 64: intra-thread, direction uniform per lane (idx bit6 = lane bit0)
        {
            const bool desc = ((lane & 1) == 0);
            #pragma unroll
            for (int j = 32; j > 0; j >>= 1)
                #pragma unroll
                for (int e = 0; e < VPT; ++e) {
                    const int f = e ^ j;
                    if (f > e) ce(v[e], v[f], desc);
                }
        }
        // k = 128..4096: cross-lane shuffle stages (j=k/2..64), then intra tail
        #pragma unroll
        for (int kk = 1; kk <= 6; ++kk) {
            const int k = 64 << kk;
            const bool desc = ((lane & (k >> 6)) == 0);   // idx&k = lane&(k>>6)
            #pragma unroll
            for (int d = k >> 7; d > 0; d >>= 1) {        // j = d*64
                const bool keepmax = (((lane & d) == 0) == desc);
                #pragma unroll
                for (int e = 0; e < VPT; ++e) {
                    const float s = __shfl_xor(v[e], d, 64);
                    v[e] = keepmax ? fmaxf(v[e], s) : fminf(v[e], s);
                }
            }
            #pragma unroll
            for (int j = 32; j > 0; j >>= 1)
                #pragma unroll
                for (int e = 0; e < VPT; ++e) {
                    const int f = e ^ j;
                    if (f > e) ce(v[e], v[f], desc);
                }
        }

        // ---- emit percentile ranks straight from registers ----
        // ranks = round(linspace(1,4095,256)); inverse test proven on HW.
        #pragma unroll
        for (int e = 0; e < VPT; ++e) {
            const int idx = lane * VPT + e;
            const int i = (int)roundf((float)(idx - 1) * (255.0f / 4094.0f));
            if (i >= 0 && i < NPOOL) {
                const int rk = (int)roundf(1.0f + (float)i * (4094.0f / 255.0f));
                if (rk == idx)
                    out[((size_t)(b * M_MAPS + m0 + 8 * p + w)) * NPOOL + i] = v[e];
            }
        }
    }
}

extern "C" void kernel_launch(void* const* d_in, const int* in_sizes, int n_in,
                              void* d_out, int out_size, void* d_ws, size_t ws_size,
                              hipStream_t stream) {
    const float* x = (const float*)d_in[0];
    float* out = (float*)d_out;
    (void)in_sizes; (void)n_in; (void)out_size;

    const size_t nelem = (size_t)NBATCH * M_MAPS * F_DIM;
    const size_t need  = 2 * nelem * sizeof(unsigned short);   // hi + lo
    const int grid = (NBATCH * M_MAPS) / BM;                   // 1024 blocks

    if (ws_size >= need) {
        unsigned short* hi = (unsigned short*)d_ws;
        unsigned short* lo = hi + nelem;
        cvt_split_kernel<<<2048, 256, 0, stream>>>(x, hi, lo);
        corr_mfma_sort_kernel<1><<<grid, THREADS, 0, stream>>>(x, hi, lo, out);
    } else {
        corr_mfma_sort_kernel<0><<<grid, THREADS, 0, stream>>>(x, nullptr, nullptr, out);
    }
}

// Round 13
// 1116.159 us; speedup vs baseline: 1.2745x; 1.2745x over previous
//
#include <hip/hip_runtime.h>
#include <hip/hip_bf16.h>

#define M_MAPS 4096
#define F_DIM  256
#define NPOOL  256
#define NBATCH 4
#define BM     16          // correlation rows per block (one MFMA M-tile)
#define THREADS 1024       // 16 waves: halves per-wave acc, sort fully parallel
#define NT     16          // n-tiles per wave: 4096 / (16 waves * 16 cols)
#define VPT    64          // sort elements per lane (one wave sorts one row)

typedef __attribute__((ext_vector_type(8))) short bf16x8;
typedef __attribute__((ext_vector_type(4))) float f32x4;

__device__ __forceinline__ unsigned short f2bf_bits(float f) {
    __hip_bfloat16 h = __float2bfloat16(f);
    return __builtin_bit_cast(unsigned short, h);
}
__device__ __forceinline__ float bf_bits2f(unsigned short s) {
    __hip_bfloat16 h = __builtin_bit_cast(__hip_bfloat16, s);
    return __bfloat162float(h);
}

// ---------- pre-kernel: split fp32 x into bf16 hi + bf16 lo ----------
__global__ __launch_bounds__(256)
void cvt_split_kernel(const float* __restrict__ x, unsigned short* __restrict__ hi,
                      unsigned short* __restrict__ lo) {
    const int n4 = NBATCH * M_MAPS * F_DIM / 4;
    for (int i = blockIdx.x * blockDim.x + threadIdx.x; i < n4;
         i += gridDim.x * blockDim.x) {
        float4 v = ((const float4*)x)[i];
        float f[4] = {v.x, v.y, v.z, v.w};
        unsigned short h[4], l[4];
        #pragma unroll
        for (int j = 0; j < 4; ++j) {
            h[j] = f2bf_bits(f[j]);
            l[j] = f2bf_bits(f[j] - bf_bits2f(h[j]));
        }
        ((ushort4*)hi)[i] = make_ushort4(h[0], h[1], h[2], h[3]);
        ((ushort4*)lo)[i] = make_ushort4(l[0], l[1], l[2], l[3]);
    }
}

// branchless compare-exchange; desc==true keeps the larger value in `a`.
__device__ __forceinline__ void ce(float& a, float& b, bool desc) {
    float lo = fminf(a, b), hi = fmaxf(a, b);
    a = desc ? hi : lo;
    b = desc ? lo : hi;
}

// ---------- main kernel: MFMA corr + wave-private register bitonic sort ----------
// 16 waves: acc is 64 regs/lane (NT=16), so acc+v[64] fits the unified
// VGPR/AGPR file without the ~90-reg/thread scratch spills that r10/r12
// showed at NT=32 (WRITE_SIZE 400 MB -> expect ~16 MB).
template<int WS>
__global__ __launch_bounds__(THREADS, 1)
void corr_mfma_sort_kernel(const float* __restrict__ x,
                           const unsigned short* __restrict__ hi,
                           const unsigned short* __restrict__ lo,
                           float* __restrict__ out) {
    __shared__ float rows[8 * M_MAPS];   // 128 KB: 8 rows per dump group

    const int tid  = threadIdx.x;
    const int lane = tid & 63;
    const int w    = tid >> 6;                    // wave 0..15
    const int g    = blockIdx.x;
    // XCD-aware mapping: 2 XCDs per batch so each batch panel stays L2-local
    const int b    = (g & 7) >> 1;                // batch 0..3
    const int gi   = ((g >> 3) << 1) | (g & 1);   // 0..255 within batch
    const int m0   = gi * BM;

    const int lr = lane & 15;                     // A-row / B-col within tile
    const int lg = lane >> 4;                     // k-group 0..3
    const int base = b * (M_MAPS * F_DIM);

    auto load_hl = [&](int off, bf16x8& oh, bf16x8& ol) {
        if constexpr (WS) {
            oh = *(const bf16x8*)(hi + base + off);
            ol = *(const bf16x8*)(lo + base + off);
        } else {
            const float* p = x + base + off;
            float4 f0 = *(const float4*)(p);
            float4 f1 = *(const float4*)(p + 4);
            float f[8] = {f0.x,f0.y,f0.z,f0.w, f1.x,f1.y,f1.z,f1.w};
            #pragma unroll
            for (int e = 0; e < 8; ++e) {
                unsigned short hbit = f2bf_bits(f[e]);
                oh[e] = (short)hbit;
                ol[e] = (short)f2bf_bits(f[e] - bf_bits2f(hbit));
            }
        }
    };

    // ---- A fragments: block's 16 rows, K=256 (8 chunks), hi+lo ----
    bf16x8 a_hi[8], a_lo[8];
    #pragma unroll
    for (int kk = 0; kk < 8; ++kk)
        load_hl((m0 + lr) * F_DIM + kk * 32 + lg * 8, a_hi[kk], a_lo[kk]);

    // ---- GEMM: 16 x 4096; each wave owns 16 column-tiles (w*16 + t*256) ----
    f32x4 acc[NT];
    #pragma unroll
    for (int t = 0; t < NT; ++t) acc[t] = (f32x4){0.f, 0.f, 0.f, 0.f};

    #pragma unroll
    for (int t = 0; t < NT; ++t) {
        const int n = t * 256 + w * 16 + lr;      // B col = corr column
        const int rowoff = n * F_DIM + lg * 8;
        #pragma unroll
        for (int kk = 0; kk < 8; ++kk) {
            bf16x8 b_hi, b_lo;
            load_hl(rowoff + kk * 32, b_hi, b_lo);
            acc[t] = __builtin_amdgcn_mfma_f32_16x16x32_bf16(a_hi[kk], b_hi, acc[t], 0, 0, 0);
            acc[t] = __builtin_amdgcn_mfma_f32_16x16x32_bf16(a_lo[kk], b_hi, acc[t], 0, 0, 0);
            acc[t] = __builtin_amdgcn_mfma_f32_16x16x32_bf16(a_hi[kk], b_lo, acc[t], 0, 0, 0);
            acc[t] = __builtin_amdgcn_mfma_f32_16x16x32_bf16(a_lo[kk], b_lo, acc[t], 0, 0, 0);
        }
    }

    // ---- dump 16 rows in two groups, then ALL 16 waves sort concurrently ----
    // C/D layout (m89/m91): col = lane&15 (-> lr), row = lg*4 + j.
    // Swizzle pos(c) = c ^ (((c>>6)&15)<<2); on the write side (c>>6)&15 is
    // lane-uniform per (wave,t) since w*16+lr never crosses a 64 boundary.
    const float scale = 1.0f / F_DIM;
    float v[VPT];

    // dump group 0: C-rows 0..7 (lanes lg 0,1 of every wave)
    if (lg < 2) {
        #pragma unroll
        for (int t = 0; t < NT; ++t) {
            const int c  = t * 256 + w * 16 + lr;
            const int pc = c ^ (((c >> 6) & 15) << 2);
            #pragma unroll
            for (int j = 0; j < 4; ++j)
                rows[(lg * 4 + j) * M_MAPS + pc] = acc[t][j] * scale;
        }
    }
    __syncthreads();

    // waves 0..7 pick up rows 0..7
    if (w < 8) {
        #pragma unroll
        for (int i = 0; i < 16; ++i) {
            const int c  = lane * VPT + i * 4;
            const int pc = c ^ ((lane & 15) << 2);   // (c>>6)&15 == lane&15
            f32x4 q = *(const f32x4*)&rows[w * M_MAPS + pc];
            v[i*4+0] = q[0]; v[i*4+1] = q[1]; v[i*4+2] = q[2]; v[i*4+3] = q[3];
        }
    }
    __syncthreads();

    // dump group 1: C-rows 8..15 (lanes lg 2,3) — acc dead afterwards
    if (lg >= 2) {
        #pragma unroll
        for (int t = 0; t < NT; ++t) {
            const int c  = t * 256 + w * 16 + lr;
            const int pc = c ^ (((c >> 6) & 15) << 2);
            #pragma unroll
            for (int j = 0; j < 4; ++j)
                rows[((lg - 2) * 4 + j) * M_MAPS + pc] = acc[t][j] * scale;
        }
    }
    __syncthreads();

    // waves 8..15 pick up rows 8..15
    if (w >= 8) {
        #pragma unroll
        for (int i = 0; i < 16; ++i) {
            const int c  = lane * VPT + i * 4;
            const int pc = c ^ ((lane & 15) << 2);
            f32x4 q = *(const f32x4*)&rows[(w - 8) * M_MAPS + pc];
            v[i*4+0] = q[0]; v[i*4+1] = q[1]; v[i*4+2] = q[2]; v[i*4+3] = q[3];
        }
    }

    // ---- wave-private descending bitonic sort: 4096 = 64 lanes x 64 elems ----
    // global index idx = lane*64 + e
    // k = 2..32: intra-thread, direction compile-time per element
    #pragma unroll
    for (int k = 2; k <= 32; k <<= 1)
        #pragma unroll
        for (int j = k >> 1; j > 0; j >>= 1)
            #pragma unroll
            for (int e = 0; e < VPT; ++e) {
                const int f = e ^ j;
                if (f > e) ce(v[e], v[f], (e & k) == 0);
            }
    // k = 64: intra-thread, direction uniform per lane (idx bit6 = lane bit0)
    {
        const bool desc = ((lane & 1) == 0);
        #pragma unroll
        for (int j = 32; j > 0; j >>= 1)
            #pragma unroll
            for (int e = 0; e < VPT; ++e) {
                const int f = e ^ j;
                if (f > e) ce(v[e], v[f], desc);
            }
    }
    // k = 128..4096: cross-lane shuffle stages (j=k/2..64), then intra tail
    #pragma unroll
    for (int kk = 1; kk <= 6; ++kk) {
        const int k = 64 << kk;
        const bool desc = ((lane & (k >> 6)) == 0);   // idx&k = lane&(k>>6)
        #pragma unroll
        for (int d = k >> 7; d > 0; d >>= 1) {        // j = d*64
            const bool keepmax = (((lane & d) == 0) == desc);
            #pragma unroll
            for (int e = 0; e < VPT; ++e) {
                const float s = __shfl_xor(v[e], d, 64);
                v[e] = keepmax ? fmaxf(v[e], s) : fminf(v[e], s);
            }
        }
        #pragma unroll
        for (int j = 32; j > 0; j >>= 1)
            #pragma unroll
            for (int e = 0; e < VPT; ++e) {
                const int f = e ^ j;
                if (f > e) ce(v[e], v[f], desc);
            }
    }

    // ---- emit percentile ranks straight from registers ----
    // ranks = round(linspace(1,4095,256)); inverse test proven on HW.
    #pragma unroll
    for (int e = 0; e < VPT; ++e) {
        const int idx = lane * VPT + e;
        const int i = (int)roundf((float)(idx - 1) * (255.0f / 4094.0f));
        if (i >= 0 && i < NPOOL) {
            const int rk = (int)roundf(1.0f + (float)i * (4094.0f / 255.0f));
            if (rk == idx)
                out[((size_t)(b * M_MAPS + m0 + w)) * NPOOL + i] = v[e];
        }
    }
}

extern "C" void kernel_launch(void* const* d_in, const int* in_sizes, int n_in,
                              void* d_out, int out_size, void* d_ws, size_t ws_size,
                              hipStream_t stream) {
    const float* x = (const float*)d_in[0];
    float* out = (float*)d_out;
    (void)in_sizes; (void)n_in; (void)out_size;

    const size_t nelem = (size_t)NBATCH * M_MAPS * F_DIM;
    const size_t need  = 2 * nelem * sizeof(unsigned short);   // hi + lo
    const int grid = (NBATCH * M_MAPS) / BM;                   // 1024 blocks

    if (ws_size >= need) {
        unsigned short* hi = (unsigned short*)d_ws;
        unsigned short* lo = hi + nelem;
        cvt_split_kernel<<<2048, 256, 0, stream>>>(x, hi, lo);
        corr_mfma_sort_kernel<1><<<grid, THREADS, 0, stream>>>(x, hi, lo, out);
    } else {
        corr_mfma_sort_kernel<0><<<grid, THREADS, 0, stream>>>(x, nullptr, nullptr, out);
    }
}